// Round 1
// 989.538 us; speedup vs baseline: 1.0286x; 1.0286x over previous
//
#include <hip/hip_runtime.h>

constexpr int E_EDGES = 500000;
constexpr int N_NODES = 20000;
constexpr int H       = 8;
constexpr int ROW     = 256;      // H*S = H*C*D floats per edge/node row (1024 B)
constexpr int CAP     = 128;      // per-node edge-list capacity (mean deg 25)
constexpr float SCALE = 0.0625f;  // 1/sqrt(H*S) = 1/16

typedef float f4 __attribute__((ext_vector_type(4)));

// ---- workspace layout (32-bit words) ----
// den[] is GONE: the softmax denominator is summed inside node_gather (it reads
// every edge's ex anyway), killing 4M contended float atomics in pass 1.
constexpr int OFF_COUNT = 0;                        // N ints (per-node degree)
constexpr int OFF_POS   = OFF_COUNT + N_NODES;      // N*CAP ints (per-node edge lists)
constexpr int OFF_EX    = OFF_POS + N_NODES * CAP;  // E*H floats (exp of logits)
constexpr int ZERO_WORDS = N_NODES;                 // only count must start at 0

__global__ __launch_bounds__(256) void zero_ws(int* __restrict__ ws) {
    int i = blockIdx.x * 256 + threadIdx.x;
    if (i < ZERO_WORDS) ws[i] = 0;
}

// Grid-stride, 4 edges per wave-iteration. One int4 broadcast load fetches 4
// dst ids; 4 independent k-row loads (nontemporal: single-use) and 4 q-row
// gathers (cache-hot, 20 MB) pipeline within the iteration AND across
// iterations (addresses are affine in the loop counter — no load chain).
// 8-lane groups reduce each per-head dot; exp stored; lanes 0..3 append their
// edge to its dst list in parallel. 4096 blocks instead of 125k workgroups.
__global__ __launch_bounds__(256) void edge_pass1(
    const float* __restrict__ k, const float* __restrict__ q,
    const int* __restrict__ dst,
    float* __restrict__ ex, int* __restrict__ count, int* __restrict__ pos)
{
    const int lane  = threadIdx.x & 63;
    const int gwave = (blockIdx.x * 256 + threadIdx.x) >> 6;
    const int nwave = (gridDim.x * 256) >> 6;
    const int h     = lane >> 3;

    for (int e0 = gwave * 4; e0 < E_EDGES; e0 += nwave * 4) {
        const int4 d4 = *(const int4*)(dst + e0);   // e0 % 4 == 0 -> 16B aligned

        const f4 k0 = __builtin_nontemporal_load((const f4*)(k + (size_t)(e0 + 0) * ROW + lane * 4));
        const f4 k1 = __builtin_nontemporal_load((const f4*)(k + (size_t)(e0 + 1) * ROW + lane * 4));
        const f4 k2 = __builtin_nontemporal_load((const f4*)(k + (size_t)(e0 + 2) * ROW + lane * 4));
        const f4 k3 = __builtin_nontemporal_load((const f4*)(k + (size_t)(e0 + 3) * ROW + lane * 4));
        const f4 q0 = *(const f4*)(q + (size_t)d4.x * ROW + lane * 4);
        const f4 q1 = *(const f4*)(q + (size_t)d4.y * ROW + lane * 4);
        const f4 q2 = *(const f4*)(q + (size_t)d4.z * ROW + lane * 4);
        const f4 q3 = *(const f4*)(q + (size_t)d4.w * ROW + lane * 4);

        float p0 = k0.x * q0.x + k0.y * q0.y + k0.z * q0.z + k0.w * q0.w;
        float p1 = k1.x * q1.x + k1.y * q1.y + k1.z * q1.z + k1.w * q1.w;
        float p2 = k2.x * q2.x + k2.y * q2.y + k2.z * q2.z + k2.w * q2.w;
        float p3 = k3.x * q3.x + k3.y * q3.y + k3.z * q3.z + k3.w * q3.w;

        // reduce within each 8-lane head group (lanes 8h..8h+7 cover head h)
        p0 += __shfl_xor(p0, 1); p1 += __shfl_xor(p1, 1);
        p2 += __shfl_xor(p2, 1); p3 += __shfl_xor(p3, 1);
        p0 += __shfl_xor(p0, 2); p1 += __shfl_xor(p1, 2);
        p2 += __shfl_xor(p2, 2); p3 += __shfl_xor(p3, 2);
        p0 += __shfl_xor(p0, 4); p1 += __shfl_xor(p1, 4);
        p2 += __shfl_xor(p2, 4); p3 += __shfl_xor(p3, 4);

        if ((lane & 7) == 0) {
            // |p*SCALE| small -> no max-subtract needed (cancels in a=ex/den)
            ex[(size_t)(e0 + 0) * H + h] = __expf(p0 * SCALE);
            ex[(size_t)(e0 + 1) * H + h] = __expf(p1 * SCALE);
            ex[(size_t)(e0 + 2) * H + h] = __expf(p2 * SCALE);
            ex[(size_t)(e0 + 3) * H + h] = __expf(p3 * SCALE);
        }
        if (lane < 4) {   // 4 parallel list-appends, one per edge in the batch
            const int d = (lane == 0) ? d4.x : (lane == 1) ? d4.y : (lane == 2) ? d4.z : d4.w;
            const int s = atomicAdd(count + d, 1);
            if (s < CAP) pos[d * CAP + s] = e0 + lane;
        }
    }
}

// One wave per node. Whole edge list loaded up front into 2 registers/lane and
// broadcast with __shfl. Body unrolled 4x: 8 independent loads (4 ex + 4 v)
// in flight per batch so the gathered 1 KB v rows pipeline to the BW limit.
// The softmax denominator is summed here for free (dsum) — every lane of a
// head group reads the same ex values, so all 8 lanes hold the full sum.
__global__ __launch_bounds__(256) void node_gather(
    const float* __restrict__ v, const float* __restrict__ ex,
    const int* __restrict__ count, const int* __restrict__ pos,
    float* __restrict__ out)
{
    const int wave = (blockIdx.x * 256 + threadIdx.x) >> 6;
    const int lane = threadIdx.x & 63;
    if (wave >= N_NODES) return;
    const int n = wave;
    const int h = lane >> 3;

    const int deg  = min(count[n], CAP);
    const int base = n * CAP;

    int e_lo = (lane      < deg) ? pos[base + lane]      : 0;
    int e_hi = (lane + 64 < deg) ? pos[base + 64 + lane] : 0;

    f4 acc = {0.f, 0.f, 0.f, 0.f};
    float dsum = 0.f;
    int j = 0;
    for (; j + 4 <= deg; j += 4) {
        const int a0 = __shfl((j + 0 < 64) ? e_lo : e_hi, (j + 0) & 63);
        const int a1 = __shfl((j + 1 < 64) ? e_lo : e_hi, (j + 1) & 63);
        const int a2 = __shfl((j + 2 < 64) ? e_lo : e_hi, (j + 2) & 63);
        const int a3 = __shfl((j + 3 < 64) ? e_lo : e_hi, (j + 3) & 63);
        const float x0 = ex[(size_t)a0 * H + h];
        const float x1 = ex[(size_t)a1 * H + h];
        const float x2 = ex[(size_t)a2 * H + h];
        const float x3 = ex[(size_t)a3 * H + h];
        const f4 v0 = __builtin_nontemporal_load((const f4*)(v + (size_t)a0 * ROW + lane * 4));
        const f4 v1 = __builtin_nontemporal_load((const f4*)(v + (size_t)a1 * ROW + lane * 4));
        const f4 v2 = __builtin_nontemporal_load((const f4*)(v + (size_t)a2 * ROW + lane * 4));
        const f4 v3 = __builtin_nontemporal_load((const f4*)(v + (size_t)a3 * ROW + lane * 4));
        dsum += (x0 + x1) + (x2 + x3);
        acc.x += x0 * v0.x; acc.y += x0 * v0.y; acc.z += x0 * v0.z; acc.w += x0 * v0.w;
        acc.x += x1 * v1.x; acc.y += x1 * v1.y; acc.z += x1 * v1.z; acc.w += x1 * v1.w;
        acc.x += x2 * v2.x; acc.y += x2 * v2.y; acc.z += x2 * v2.z; acc.w += x2 * v2.w;
        acc.x += x3 * v3.x; acc.y += x3 * v3.y; acc.z += x3 * v3.z; acc.w += x3 * v3.w;
    }
    for (; j < deg; ++j) {
        const int a = __shfl((j < 64) ? e_lo : e_hi, j & 63);
        const float x = ex[(size_t)a * H + h];
        const f4 vv = __builtin_nontemporal_load((const f4*)(v + (size_t)a * ROW + lane * 4));
        dsum += x;
        acc.x += x * vv.x; acc.y += x * vv.y; acc.z += x * vv.z; acc.w += x * vv.w;
    }

    const float inv = 1.0f / fmaxf(dsum, 1e-9f);
    acc.x *= inv; acc.y *= inv; acc.z *= inv; acc.w *= inv;
    __builtin_nontemporal_store(acc, (f4*)(out + (size_t)n * ROW + lane * 4));
}

extern "C" void kernel_launch(void* const* d_in, const int* in_sizes, int n_in,
                              void* d_out, int out_size, void* d_ws, size_t ws_size,
                              hipStream_t stream) {
    const float* v   = (const float*)d_in[0];
    const float* k   = (const float*)d_in[1];
    const float* q   = (const float*)d_in[2];
    const int*   dst = (const int*)d_in[3];
    float* out = (float*)d_out;

    int*   count = (int*)d_ws   + OFF_COUNT;
    int*   pos   = (int*)d_ws   + OFF_POS;
    float* ex    = (float*)d_ws + OFF_EX;

    zero_ws<<<(ZERO_WORDS + 255) / 256, 256, 0, stream>>>((int*)d_ws);
    edge_pass1<<<4096, 256, 0, stream>>>(k, q, dst, ex, count, pos);
    node_gather<<<(N_NODES * 64) / 256, 256, 0, stream>>>(v, ex, count, pos, out);
}